// Round 1
// baseline (148.739 us; speedup 1.0000x reference)
//
#include <hip/hip_runtime.h>
#include <math.h>

#define N 4096
#define P 128
#define H 4
#define E 32
#define NSEG 32

// ---------------------------------------------------------------------------
// Kernel A: counting sort of row indices by segment id. Single block.
// Writes seg_rows[N] (row ids grouped by segment) and seg_off[NSEG+1].
// ---------------------------------------------------------------------------
__global__ __launch_bounds__(256) void seg_sort_kernel(const int* __restrict__ pos,
                                                       int* __restrict__ seg_rows,
                                                       int* __restrict__ seg_off) {
    __shared__ int cnt[NSEG];
    __shared__ int off[NSEG + 1];
    int t = threadIdx.x;
    if (t < NSEG) cnt[t] = 0;
    __syncthreads();
    for (int i = t; i < N; i += 256) atomicAdd(&cnt[pos[i]], 1);
    __syncthreads();
    if (t == 0) {
        int s = 0;
        for (int k = 0; k < NSEG; ++k) { off[k] = s; s += cnt[k]; }
        off[NSEG] = s;
    }
    __syncthreads();
    if (t <= NSEG) seg_off[t] = off[t];
    if (t < NSEG) cnt[t] = off[t];   // reuse as running cursor
    __syncthreads();
    for (int i = t; i < N; i += 256) {
        int r = atomicAdd(&cnt[pos[i]], 1);
        seg_rows[r] = i;
    }
}

// ---------------------------------------------------------------------------
// Kernel B: fused QKV projection. y = x @ W + b for W in {Wq,Wk,Wv}.
// Grid: (N/64 row tiles, 3 matrices). Block 256 threads.
// LDS: 64x128 x-tile (32KB) + 32x128 W chunk (16KB) = 48KB.
// Each thread computes an 8-row x 4-col micro-tile (float4 LDS reads).
// ---------------------------------------------------------------------------
__global__ __launch_bounds__(256) void proj_kernel(const float* __restrict__ x,
                                                   const float* __restrict__ Wq,
                                                   const float* __restrict__ bq,
                                                   const float* __restrict__ Wk,
                                                   const float* __restrict__ bk,
                                                   const float* __restrict__ Wv,
                                                   const float* __restrict__ bv,
                                                   float* __restrict__ Q,
                                                   float* __restrict__ Ko,
                                                   float* __restrict__ Vo) {
    __shared__ float Xl[64][128];   // 32 KB
    __shared__ float Wl[32][128];   // 16 KB

    const int mat = blockIdx.y;
    const float* W = (mat == 0) ? Wq : (mat == 1) ? Wk : Wv;
    const float* b = (mat == 0) ? bq : (mat == 1) ? bk : bv;
    float* y       = (mat == 0) ? Q  : (mat == 1) ? Ko : Vo;

    const int t  = threadIdx.x;
    const int r0 = blockIdx.x * 64;

    // stage x tile (coalesced float4)
    for (int i = t * 4; i < 64 * 128; i += 256 * 4) {
        *(float4*)((float*)Xl + i) = *(const float4*)(x + r0 * 128 + i);
    }

    const int tc = t & 31;   // cols 4*tc .. 4*tc+3
    const int tr = t >> 5;   // rows 8*tr .. 8*tr+7

    float4 bb = *(const float4*)(b + tc * 4);
    float4 acc[8];
#pragma unroll
    for (int r = 0; r < 8; ++r) acc[r] = bb;

    for (int kc = 0; kc < 128; kc += 32) {
        __syncthreads();
        for (int i = t * 4; i < 32 * 128; i += 256 * 4) {
            *(float4*)((float*)Wl + i) = *(const float4*)(W + kc * 128 + i);
        }
        __syncthreads();
#pragma unroll
        for (int k0 = 0; k0 < 32; k0 += 4) {
            float4 w0 = *(float4*)&Wl[k0 + 0][tc * 4];
            float4 w1 = *(float4*)&Wl[k0 + 1][tc * 4];
            float4 w2 = *(float4*)&Wl[k0 + 2][tc * 4];
            float4 w3 = *(float4*)&Wl[k0 + 3][tc * 4];
#pragma unroll
            for (int r = 0; r < 8; ++r) {
                float4 xv = *(float4*)&Xl[tr * 8 + r][kc + k0];
                acc[r].x = fmaf(xv.x, w0.x, acc[r].x);
                acc[r].y = fmaf(xv.x, w0.y, acc[r].y);
                acc[r].z = fmaf(xv.x, w0.z, acc[r].z);
                acc[r].w = fmaf(xv.x, w0.w, acc[r].w);
                acc[r].x = fmaf(xv.y, w1.x, acc[r].x);
                acc[r].y = fmaf(xv.y, w1.y, acc[r].y);
                acc[r].z = fmaf(xv.y, w1.z, acc[r].z);
                acc[r].w = fmaf(xv.y, w1.w, acc[r].w);
                acc[r].x = fmaf(xv.z, w2.x, acc[r].x);
                acc[r].y = fmaf(xv.z, w2.y, acc[r].y);
                acc[r].z = fmaf(xv.z, w2.z, acc[r].z);
                acc[r].w = fmaf(xv.z, w2.w, acc[r].w);
                acc[r].x = fmaf(xv.w, w3.x, acc[r].x);
                acc[r].y = fmaf(xv.w, w3.y, acc[r].y);
                acc[r].z = fmaf(xv.w, w3.z, acc[r].z);
                acc[r].w = fmaf(xv.w, w3.w, acc[r].w);
            }
        }
    }

#pragma unroll
    for (int r = 0; r < 8; ++r) {
        *(float4*)(y + (size_t)(r0 + tr * 8 + r) * 128 + tc * 4) = acc[r];
    }
}

// ---------------------------------------------------------------------------
// Kernel C: per-(segment, head) attention with online softmax.
// Grid: (NSEG, H). Block 256 threads; one query row per thread (looped if
// a segment exceeds 256 rows). K/V rows staged to LDS in chunks of CH.
// ---------------------------------------------------------------------------
#define CH 160

__global__ __launch_bounds__(256) void attn_kernel(const float* __restrict__ Q,
                                                   const float* __restrict__ K,
                                                   const float* __restrict__ V,
                                                   const int* __restrict__ seg_rows,
                                                   const int* __restrict__ seg_off,
                                                   float* __restrict__ out) {
    __shared__ float Ks[CH][E];   // 20 KB
    __shared__ float Vs[CH][E];   // 20 KB

    const int s   = blockIdx.x;
    const int h   = blockIdx.y;
    const int beg = seg_off[s];
    const int len = seg_off[s + 1] - beg;
    const int t   = threadIdx.x;
    const float scale = 0.17677669529663687f;   // 1/sqrt(32)

    for (int qb = 0; qb < len; qb += 256) {
        const int  qi     = qb + t;
        const bool active = (qi < len);
        const int  qrow   = active ? seg_rows[beg + qi] : 0;

        float q[E];
        if (active) {
#pragma unroll
            for (int e = 0; e < E; e += 4) {
                float4 v4 = *(const float4*)(Q + (size_t)qrow * P + h * E + e);
                q[e] = v4.x; q[e + 1] = v4.y; q[e + 2] = v4.z; q[e + 3] = v4.w;
            }
        }

        float m = -3.0e38f, l = 0.f;
        float acc[E];
#pragma unroll
        for (int e = 0; e < E; ++e) acc[e] = 0.f;

        for (int cb = 0; cb < len; cb += CH) {
            const int cl = min(CH, len - cb);
            __syncthreads();
            // stage K/V chunk: lanes cover consecutive e -> coalesced 128B rows
            for (int idx = t; idx < cl * E; idx += 256) {
                int r = idx >> 5, e = idx & 31;
                int krow = seg_rows[beg + cb + r];
                Ks[r][e] = K[(size_t)krow * P + h * E + e];
                Vs[r][e] = V[(size_t)krow * P + h * E + e];
            }
            __syncthreads();
            if (active) {
                for (int r = 0; r < cl; ++r) {
                    float sc = 0.f;
#pragma unroll
                    for (int e = 0; e < E; ++e) sc = fmaf(q[e], Ks[r][e], sc);
                    sc *= scale;
                    float mn   = fmaxf(m, sc);
                    float corr = __expf(m - mn);
                    float p    = __expf(sc - mn);
                    l = l * corr + p;
#pragma unroll
                    for (int e = 0; e < E; ++e)
                        acc[e] = fmaf(p, Vs[r][e], acc[e] * corr);
                    m = mn;
                }
            }
        }

        if (active) {
            float inv = 1.0f / l;
#pragma unroll
            for (int e = 0; e < E; e += 4) {
                float4 o;
                o.x = acc[e] * inv; o.y = acc[e + 1] * inv;
                o.z = acc[e + 2] * inv; o.w = acc[e + 3] * inv;
                *(float4*)(out + (size_t)qrow * P + h * E + e) = o;
            }
        }
    }
}

// ---------------------------------------------------------------------------
extern "C" void kernel_launch(void* const* d_in, const int* in_sizes, int n_in,
                              void* d_out, int out_size, void* d_ws, size_t ws_size,
                              hipStream_t stream) {
    const float* inp = (const float*)d_in[0];
    const int*   pos = (const int*)d_in[1];
    const float* Wq  = (const float*)d_in[2];
    const float* bq  = (const float*)d_in[3];
    const float* Wk  = (const float*)d_in[4];
    const float* bk  = (const float*)d_in[5];
    const float* Wv  = (const float*)d_in[6];
    const float* bv  = (const float*)d_in[7];
    float* out = (float*)d_out;

    // workspace layout: Q, K, V (N*P floats each), seg_rows[N], seg_off[NSEG+1]
    float* Q  = (float*)d_ws;
    float* Kb = Q + (size_t)N * P;
    float* Vb = Kb + (size_t)N * P;
    int* seg_rows = (int*)(Vb + (size_t)N * P);
    int* seg_off  = seg_rows + N;

    seg_sort_kernel<<<1, 256, 0, stream>>>(pos, seg_rows, seg_off);
    proj_kernel<<<dim3(N / 64, 3), 256, 0, stream>>>(inp, Wq, bq, Wk, bk, Wv, bv, Q, Kb, Vb);
    attn_kernel<<<dim3(NSEG, H), 256, 0, stream>>>(Q, Kb, Vb, seg_rows, seg_off, out);
}